// Round 13
// baseline (165.792 us; speedup 1.0000x reference)
//
#include <hip/hip_runtime.h>
#include <hip/hip_bf16.h>
#include <math.h>

#define D_MODEL 512
#define HEADS   8
#define D_K     64
#define T_SEQ   2048
#define B_SZ    4
#define NROWS   (B_SZ * T_SEQ)   // 8192
#define KVB     64
#define KSPLIT  2
#define KHALF   (T_SEQ / KSPLIT) // 1024

#define BM 128
#define BN 128
#define BKG 64

typedef __attribute__((ext_vector_type(8))) short short8;
typedef __attribute__((ext_vector_type(4))) float f32x4;
typedef __attribute__((ext_vector_type(4))) ushort bf16x4;
typedef __attribute__((ext_vector_type(4))) unsigned int u32x4;

typedef __attribute__((address_space(1))) const unsigned int as1_uint;
typedef __attribute__((address_space(3))) unsigned int as3_uint;

__device__ __forceinline__ ushort f2bf(float f) {
    union { float f; unsigned u; } v; v.f = f;
    unsigned u = v.u;
    unsigned r = (u + 0x7FFFu + ((u >> 16) & 1u)) >> 16;
    return (ushort)r;
}
__device__ __forceinline__ float bf2f(ushort u) {
    union { unsigned u; float f; } v; v.u = ((unsigned)u) << 16;
    return v.f;
}
__device__ __forceinline__ unsigned pk_bf16(float lo, float hi) {
    unsigned r;
    asm("v_cvt_pk_bf16_f32 %0, %1, %2" : "=v"(r) : "v"(lo), "v"(hi));
    return r;
}

// ---------------------------------------------------------------- fused prep
__global__ __launch_bounds__(256) void k_prep(
    const int* __restrict__ tokens, const float* __restrict__ emb,
    const float* __restrict__ wq, const float* __restrict__ wk,
    const float* __restrict__ wv, const float* __restrict__ wo,
    const float* __restrict__ w1, const float* __restrict__ w2,
    const float* __restrict__ bq, const float* __restrict__ bk,
    const float* __restrict__ bv,
    ushort* __restrict__ xb, float* __restrict__ mask_out,
    ushort* __restrict__ wqkvT, ushort* __restrict__ woT,
    ushort* __restrict__ w1T, ushort* __restrict__ w2T,
    float* __restrict__ bqkv, float qsc)
{
    __shared__ ushort tls[32][33];
    int bid = blockIdx.x, tid = threadIdx.x;
    if (bid < 4096) {
        int row = bid * 2 + (tid >> 7);
        int t   = row & (T_SEQ - 1);
        int tok = tokens[row];
        int t2  = tid & 127;
        if (t2 == 0) mask_out[row] = (tok == 0) ? 1.0f : 0.0f;
        const float* e = emb + (size_t)tok * D_MODEL;
#pragma unroll
        for (int i = 0; i < 4; ++i) {
            int d = t2 + 128 * i;
            float freq = exp2f(-(float)(d & ~1) * 0.025952563240330564f);
            float sn, cs;
            sincosf((float)t * freq, &sn, &cs);
            float x = e[d] * 22.627416997969522f + ((d & 1) ? cs : sn);
            xb[(size_t)row * D_MODEL + d] = f2bf(x);
        }
        return;
    }
    const float* src; ushort* dst; float scale = 1.0f; int K, N, bx, by;
    if (bid < 5120) {
        int b = bid - 4096; int z = b >> 8; int rem = b & 255;
        bx = rem & 15; by = rem >> 4; K = 512; N = 512;
        src = (z == 0) ? wq : (z == 1) ? wk : (z == 2) ? wv : wo;
        dst = (z < 3) ? wqkvT + (size_t)z * 512 * 512 : woT;
        scale = (z == 0) ? qsc : 1.0f;
    } else if (bid < 5632) {
        int b = bid - 5120; bx = b & 31; by = b >> 5; K = 512; N = 1024; src = w1; dst = w1T;
    } else if (bid < 6144) {
        int b = bid - 5632; bx = b & 15; by = b >> 4; K = 1024; N = 512; src = w2; dst = w2T;
    } else {
        int i = (bid - 6144) * 256 + tid;
        if (i < 512)       bqkv[i] = bq[i] * qsc;
        else if (i < 1024) bqkv[i] = bk[i - 512];
        else if (i < 1536) bqkv[i] = bv[i - 1024];
        return;
    }
    int tx = tid & 31, ty = tid >> 5;
    int n0 = bx * 32, k0 = by * 32;
#pragma unroll
    for (int i = 0; i < 4; ++i)
        tls[ty + i * 8][tx] = f2bf(src[(size_t)(k0 + ty + i * 8) * N + n0 + tx] * scale);
    __syncthreads();
#pragma unroll
    for (int i = 0; i < 4; ++i)
        dst[(size_t)(n0 + ty + i * 8) * K + k0 + tx] = tls[tx][ty + i * 8];
}

// ---------------------------------------------------------------- LDS-staged GEMM
template<int MODE, bool RELU>
__global__ __launch_bounds__(256) void k_gemm_lds(
    const ushort* __restrict__ A, const ushort* __restrict__ BT,
    const float* __restrict__ bias, void* __restrict__ C0,
    void* __restrict__ C1, void* __restrict__ C2,
    int M, int N, int K)
{
    __shared__ __attribute__((aligned(16))) ushort As[2][BM * BKG];
    __shared__ __attribute__((aligned(16))) ushort Bs[2][BN * BKG];

    const int tid = threadIdx.x;
    const int w = tid >> 6, l = tid & 63;
    const int lr = l & 15, lg = l >> 4;
    const int wr = w >> 1, wc = w & 1;

    int bx = blockIdx.x, by = blockIdx.y;
    {   // XCD-aware swizzle (bijective; gridDim.y % 8 == 0 for all our calls)
        int nx = gridDim.x, ny = gridDim.y;
        if ((ny & 7) == 0) {
            int lin = bx + nx * by;
            int xcd = lin & 7, idx = lin >> 3;
            int per = ny >> 3;
            by = xcd * per + (idx % per);
            bx = idx / per;
        }
    }
    const int brow0 = by * BM;
    const int bcol0 = bx * BN;
    const int gi0 = w * 256 + l;
    const int swz = lr & 7;

    f32x4 acc[4][4] = {};
    const int nks = K >> 6;

#define STAGE(buf, k0)                                                          \
    {                                                                           \
        _Pragma("unroll")                                                       \
        for (int i = 0; i < 4; ++i) {                                           \
            int gi = gi0 + i * 64;                                              \
            int row = gi >> 3, slot = gi & 7;                                   \
            int g = slot ^ (row & 7);                                           \
            __builtin_amdgcn_global_load_lds(                                   \
                (as1_uint*)(A + (size_t)(brow0 + row) * K + (k0) + g * 8),      \
                (as3_uint*)(&As[buf][gi * 8]), 16, 0, 0);                       \
            __builtin_amdgcn_global_load_lds(                                   \
                (as1_uint*)(BT + (size_t)(bcol0 + row) * K + (k0) + g * 8),     \
                (as3_uint*)(&Bs[buf][gi * 8]), 16, 0, 0);                       \
        }                                                                       \
    }

    STAGE(0, 0);
    __syncthreads();

    int buf = 0;
    for (int ks = 0; ks < nks; ++ks) {
        if (ks + 1 < nks) STAGE(buf ^ 1, (ks + 1) * BKG);
#pragma unroll
        for (int kk = 0; kk < 2; ++kk) {
            short8 af[4], bfr[4];
#pragma unroll
            for (int m = 0; m < 4; ++m) {
                int row = wr * 64 + m * 16 + lr;
                int slot = (kk * 4 + lg) ^ swz;
                af[m] = *(const short8*)(&As[buf][row * 64 + slot * 8]);
            }
#pragma unroll
            for (int n = 0; n < 4; ++n) {
                int row = wc * 64 + n * 16 + lr;
                int slot = (kk * 4 + lg) ^ swz;
                bfr[n] = *(const short8*)(&Bs[buf][row * 64 + slot * 8]);
            }
#pragma unroll
            for (int m = 0; m < 4; ++m)
#pragma unroll
                for (int n = 0; n < 4; ++n)
                    acc[m][n] = __builtin_amdgcn_mfma_f32_16x16x32_bf16(af[m], bfr[n], acc[m][n], 0, 0, 0);
        }
        __syncthreads();
        buf ^= 1;
    }
#undef STAGE

#pragma unroll
    for (int n = 0; n < 4; ++n) {
        int col = bcol0 + wc * 64 + n * 16 + lr;
        float bv = bias[col];
#pragma unroll
        for (int m = 0; m < 4; ++m) {
            int row0 = brow0 + wr * 64 + m * 16 + 4 * lg;
            if constexpr (MODE == 2) {
                int seg = col >> 9, lc = col & 511;
                if (seg == 2) {
                    bf16x4 pk;
#pragma unroll
                    for (int j = 0; j < 4; ++j) pk[j] = f2bf(acc[m][n][j] + bv);
                    *(bf16x4*)((ushort*)C2 + (size_t)lc * M + row0) = pk;
                } else {
                    ushort* dst = (seg == 0) ? (ushort*)C0 : (ushort*)C1;
#pragma unroll
                    for (int j = 0; j < 4; ++j)
                        dst[(size_t)(row0 + j) * 512 + lc] = f2bf(acc[m][n][j] + bv);
                }
            } else if constexpr (MODE == 0) {
#pragma unroll
                for (int j = 0; j < 4; ++j) {
                    float v = acc[m][n][j] + bv;
                    if (RELU) v = fmaxf(v, 0.0f);
                    ((ushort*)C0)[(size_t)(row0 + j) * N + col] = f2bf(v);
                }
            } else {
#pragma unroll
                for (int j = 0; j < 4; ++j)
                    ((float*)C0)[(size_t)(row0 + j) * N + col] = acc[m][n][j] + bv;
            }
        }
    }
}

// ---------------------------------------------------------------- flash attention
// KSPLIT=2: 1024 blocks (512 thr = 8 waves), each covers 128 q rows x 1024 keys
// of one (b,h). Static-max exp2 softmax => partials are exactly additive.
// Writes unnormalized O (bf16) + l (f32); k_comb merges.
__global__ __launch_bounds__(512, 8) void k_attn(
    const ushort* __restrict__ Q, const ushort* __restrict__ Kb,
    const ushort* __restrict__ Vt, const int* __restrict__ tokens,
    ushort* __restrict__ O0, ushort* __restrict__ O1,
    float* __restrict__ lp)
{
    __shared__ __attribute__((aligned(16))) ushort Kl[2][KVB * 64];
    __shared__ __attribute__((aligned(16))) ushort Vl[2][KVB * 64];
    __shared__ __attribute__((aligned(16))) ushort Mbh[KHALF];   // bf16 mask
    __shared__ int padf[KHALF / KVB];

    const int tid = threadIdx.x;
    const int w = tid >> 6, l = tid & 63;
    const int lr = l & 15, lg = l >> 4;
    const int swz = lr & 7;

    // XCD swizzle: each (b,h,ks) group's 16 q-blocks co-resident on one XCD
    int lin = blockIdx.x + 16 * blockIdx.y + 256 * blockIdx.z;  // 0..1023
    int xcd = lin & 7, idx = lin >> 3;          // idx 0..127
    int group = xcd + 8 * (idx >> 4);           // 0..63
    int qt = idx & 15;
    int ks = group & 1;
    int h  = (group >> 1) & 7;
    int b  = group >> 4;

    const int q0  = qt * 128 + w * 16;
    const int kb0 = ks * KHALF;

    // staging geometry: thread -> row srow (0..63), granule sg (0..7)
    const int gi   = w * 64 + l;
    const int srow = gi >> 3;
    const int sg   = gi & 7;
    const int sgx  = sg ^ (srow & 7);
    const ushort* Ksrc = Kb + ((size_t)(b * T_SEQ + kb0) + srow) * D_MODEL + h * D_K + sgx * 8;
    const int kbase = 32 * (sg >> 2) + 8 * ((sg >> 1) & 1) + 4 * (sg & 1);
    const ushort* Vsrc = Vt + (size_t)(h * D_K + srow) * NROWS + b * T_SEQ + kb0 + kbase;
    const int vds = srow * 128 + sgx * 16;

#define KSTAGE(bufi, kt_)                                                       \
    __builtin_amdgcn_global_load_lds(                                           \
        (as1_uint*)(Ksrc + (size_t)(kt_) * KVB * D_MODEL),                      \
        (as3_uint*)(&Kl[bufi][gi * 8]), 16, 0, 0);

    const ushort* Qh = Q + (size_t)b * T_SEQ * D_MODEL + h * D_K;
    short8 aq[2];
#pragma unroll
    for (int c2 = 0; c2 < 2; ++c2)
        aq[c2] = *(const short8*)(Qh + (size_t)(q0 + lr) * D_MODEL + c2 * 32 + 8 * lg);

    // mask staging (bf16) + per-tile pad bitmap for this key half
    const int* tk = tokens + b * T_SEQ + kb0;
#pragma unroll
    for (int it = 0; it < KHALF / 512; ++it) {
        int i = tid + it * 512;
        bool pad = (tk[i] == 0);
        Mbh[i] = pad ? (ushort)0xFF7F : (ushort)0;
        unsigned long long bal = __ballot(pad);
        if (l == 0) padf[it * 8 + w] = (bal != 0ull);
    }

    float l_run = 0.0f;
    f32x4 acc[4] = {};

    // prologue: tile 0
    {
        bf16x4 va = *(const bf16x4*)(Vsrc);
        bf16x4 vb2 = *(const bf16x4*)(Vsrc + 16);
        KSTAGE(0, 0);
        u32x4 pk = { ((const unsigned*)&va)[0], ((const unsigned*)&va)[1],
                     ((const unsigned*)&vb2)[0], ((const unsigned*)&vb2)[1] };
        *(u32x4*)((char*)Vl[0] + vds) = pk;
    }
    __syncthreads();

    int buf = 0;
    const int NT = KHALF / KVB;   // 16
    for (int kt = 0; kt < NT; ++kt) {
        bf16x4 vna, vnb;
        bool more = (kt + 1 < NT);
        if (more) {
            KSTAGE(buf ^ 1, kt + 1);
            vna = *(const bf16x4*)(Vsrc + (kt + 1) * KVB);
            vnb = *(const bf16x4*)(Vsrc + (kt + 1) * KVB + 16);
        }

        const ushort* Kt = Kl[buf];
        const ushort* Vb = Vl[buf];

        // ---- QK^T (swapped): s[kb][j] = S[q=q0+lr][key = kb0 + kt*64 + 16kb + 4lg + j]
        f32x4 s[4];
        __builtin_amdgcn_s_setprio(1);
#pragma unroll
        for (int kb = 0; kb < 4; ++kb) {
            f32x4 sf = {};
#pragma unroll
            for (int c2 = 0; c2 < 2; ++c2) {
                short8 bk = *(const short8*)((const char*)Kt
                            + (kb * 16 + lr) * 128 + (((c2 * 4 + lg) ^ swz) * 16));
                sf = __builtin_amdgcn_mfma_f32_16x16x32_bf16(bk, aq[c2], sf, 0, 0, 0);
            }
            s[kb] = sf;
        }
        __builtin_amdgcn_s_setprio(0);

        // ---- mask add only when tile has a pad key (rare)
        if (padf[kt]) {
            const ushort* mrow = Mbh + kt * KVB + 4 * lg;
#pragma unroll
            for (int kb = 0; kb < 4; ++kb) {
                bf16x4 m4 = *(const bf16x4*)(mrow + kb * 16);
#pragma unroll
                for (int j = 0; j < 4; ++j) s[kb][j] += bf2f(m4[j]);
            }
        }

        // ---- P = exp2(S) (static max); lane-local sum + 2 shfl
        float pv[4][4];
        float ts = 0.0f;
#pragma unroll
        for (int kb = 0; kb < 4; ++kb)
#pragma unroll
            for (int j = 0; j < 4; ++j) {
                float pe = exp2f(s[kb][j]);
                pv[kb][j] = pe;
                ts += pe;
            }
        ts += __shfl_xor(ts, 16);
        ts += __shfl_xor(ts, 32);
        l_run += ts;

        // ---- P -> bf16 pairs; PV B-fragments assembled in-register
        unsigned dw[4][2];
#pragma unroll
        for (int kb = 0; kb < 4; ++kb) {
            dw[kb][0] = pk_bf16(pv[kb][0], pv[kb][1]);
            dw[kb][1] = pk_bf16(pv[kb][2], pv[kb][3]);
        }
        u32x4 pw0 = { dw[0][0], dw[0][1], dw[1][0], dw[1][1] };
        u32x4 pw1 = { dw[2][0], dw[2][1], dw[3][0], dw[3][1] };
        short8 pa0 = __builtin_bit_cast(short8, pw0);
        short8 pa1 = __builtin_bit_cast(short8, pw1);

        // ---- PV (swapped): acc[c][j] = O^T[d = c*16+4lg+j][q = q0+lr]
        __builtin_amdgcn_s_setprio(1);
#pragma unroll
        for (int c = 0; c < 4; ++c) {
            short8 bv0 = *(const short8*)((const char*)Vb
                         + (c * 16 + lr) * 128 + ((lg ^ swz) * 16));
            acc[c] = __builtin_amdgcn_mfma_f32_16x16x32_bf16(bv0, pa0, acc[c], 0, 0, 0);
            short8 bv1 = *(const short8*)((const char*)Vb
                         + (c * 16 + lr) * 128 + (((4 + lg) ^ swz) * 16));
            acc[c] = __builtin_amdgcn_mfma_f32_16x16x32_bf16(bv1, pa1, acc[c], 0, 0, 0);
        }
        __builtin_amdgcn_s_setprio(0);

        // ---- write next V tile
        if (more) {
            u32x4 pk = { ((const unsigned*)&vna)[0], ((const unsigned*)&vna)[1],
                         ((const unsigned*)&vnb)[0], ((const unsigned*)&vnb)[1] };
            *(u32x4*)((char*)Vl[buf ^ 1] + vds) = pk;
        }
        __syncthreads();
        buf ^= 1;
    }
#undef KSTAGE

    // ---- unnormalized partial output + l partial
    ushort* Op = (ks == 0) ? O0 : O1;
    ushort* orow = Op + (size_t)(b * T_SEQ + q0 + lr) * D_MODEL + h * D_K;
#pragma unroll
    for (int c = 0; c < 4; ++c) {
        bf16x4 pk;
#pragma unroll
        for (int j = 0; j < 4; ++j) pk[j] = f2bf(acc[c][j]);
        *(bf16x4*)(orow + c * 16 + 4 * lg) = pk;
    }
    if (l < 16)
        lp[(size_t)(ks * 8 + h) * NROWS + b * T_SEQ + q0 + l] = l_run;
}

// ---------------------------------------------------------------- combine partials
// out = (O0 + O1) / (l0 + l1), in-place into O0. 8 elems/thread.
__global__ __launch_bounds__(256) void k_comb(
    ushort* __restrict__ O0, const ushort* __restrict__ O1,
    const float* __restrict__ lp)
{
    int g = blockIdx.x * 256 + threadIdx.x;
    int row = g >> 6, seg = g & 63;
    int h = seg >> 3;
    size_t off = (size_t)row * D_MODEL + seg * 8;
    short8 a = *(const short8*)(O0 + off);
    short8 c = *(const short8*)(O1 + off);
    float l0 = lp[(size_t)h * NROWS + row];
    float l1 = lp[(size_t)(8 + h) * NROWS + row];
    float rl = 1.0f / (l0 + l1);
    short8 r;
#pragma unroll
    for (int i = 0; i < 8; ++i)
        r[i] = (short)f2bf((bf2f((ushort)a[i]) + bf2f((ushort)c[i])) * rl);
    *(short8*)(O0 + off) = r;
}

// ---------------------------------------------------------------- add + layernorm
template<bool A_BF16, bool RES_BF16, bool OUT_F32>
__global__ __launch_bounds__(256) void k_ln(
    const void* __restrict__ A, const void* __restrict__ Res,
    const float* __restrict__ g, const float* __restrict__ bb,
    float* __restrict__ of, ushort* __restrict__ ob)
{
    int row = blockIdx.x * 4 + (threadIdx.x >> 6);
    int l = threadIdx.x & 63;
    float v[8];
    float s = 0.0f, ss = 0.0f;
#pragma unroll
    for (int i = 0; i < 2; ++i) {
        int d0 = i * 256 + l * 4;
        f32x4 va, vb;
        if (A_BF16) {
            bf16x4 t = *(const bf16x4*)((const ushort*)A + (size_t)row * D_MODEL + d0);
#pragma unroll
            for (int j = 0; j < 4; ++j) va[j] = bf2f(t[j]);
        } else {
            va = *(const f32x4*)((const float*)A + (size_t)row * D_MODEL + d0);
        }
        if (RES_BF16) {
            bf16x4 t = *(const bf16x4*)((const ushort*)Res + (size_t)row * D_MODEL + d0);
#pragma unroll
            for (int j = 0; j < 4; ++j) vb[j] = bf2f(t[j]);
        } else {
            vb = *(const f32x4*)((const float*)Res + (size_t)row * D_MODEL + d0);
        }
#pragma unroll
        for (int j = 0; j < 4; ++j) {
            float x = va[j] + vb[j];
            v[i * 4 + j] = x; s += x; ss += x * x;
        }
    }
#pragma unroll
    for (int d = 1; d < 64; d <<= 1) { s += __shfl_xor(s, d); ss += __shfl_xor(ss, d); }
    float mu  = s * (1.0f / 512.0f);
    float var = ss * (1.0f / 512.0f) - mu * mu;
    float rs  = rsqrtf(var + 1e-5f);
#pragma unroll
    for (int i = 0; i < 2; ++i)
#pragma unroll
        for (int j = 0; j < 4; ++j) {
            int d = i * 256 + l * 4 + j;
            float o = (v[i * 4 + j] - mu) * rs * g[d] + bb[d];
            if (OUT_F32) of[(size_t)row * D_MODEL + d] = o;
            else         ob[(size_t)row * D_MODEL + d] = f2bf(o);
        }
}

// ---------------------------------------------------------------- launcher
extern "C" void kernel_launch(void* const* d_in, const int* in_sizes, int n_in,
                              void* d_out, int out_size, void* d_ws, size_t ws_size,
                              hipStream_t stream)
{
    const int*   tokens = (const int*)  d_in[0];
    const float* emb    = (const float*)d_in[1];
    const float* wq     = (const float*)d_in[2];
    const float* bq     = (const float*)d_in[3];
    const float* wk     = (const float*)d_in[4];
    const float* bk     = (const float*)d_in[5];
    const float* wv     = (const float*)d_in[6];
    const float* bv     = (const float*)d_in[7];
    const float* wo     = (const float*)d_in[8];
    const float* bo     = (const float*)d_in[9];
    const float* w1     = (const float*)d_in[10];
    const float* b1     = (const float*)d_in[11];
    const float* w2     = (const float*)d_in[12];
    const float* b2     = (const float*)d_in[13];
    const float* ln1_g  = (const float*)d_in[14];
    const float* ln1_b  = (const float*)d_in[15];
    const float* ln2_g  = (const float*)d_in[16];
    const float* ln2_b  = (const float*)d_in[17];

    char* ws = (char*)d_ws;
    ushort* xb   = (ushort*)(ws + 0);              //  8 MB  x bf16 (LN1 residual)
    ushort* Qb   = (ushort*)(ws + 8388608);        //  8 MB  Q; later h bf16
    ushort* Kbuf = (ushort*)(ws + 16777216);       //  8 MB  K \ later ff1 (16 MB)
    ushort* Vt   = (ushort*)(ws + 25165824);       //  8 MB  V^T [512][8192] /
    ushort* atb  = (ushort*)(ws + 33554432);       //  8 MB  O-partial0 -> attn out
    ushort* AVb  = (ushort*)(ws + 41943040);       //  8 MB  O-partial1 -> WO out -> ff2
    ushort* wqkvT = (ushort*)(ws + 50331648);      // 1.5 MB
    ushort* woT  = wqkvT + 1536 * 512;
    ushort* w1T  = woT + 262144;
    ushort* w2T  = w1T + 524288;
    float*  bqkv = (float*)(w2T + 524288);         // 6 KB
    float*  lpart = bqkv + 2048;                   // 512 KB (2*8*8192 f32)

    ushort* hb   = Qb;
    ushort* ff1b = Kbuf;
    ushort* ff2b = AVb;

    float* out_f    = (float*)d_out;
    float* mask_out = out_f + (size_t)NROWS * D_MODEL;

    // exp2-domain score scale: 1/sqrt(64) * log2(e)
    const float QSC = 0.18033688011112042f;

    k_prep<<<6150, 256, 0, stream>>>(
        tokens, emb, wq, wk, wv, wo, w1, w2, bq, bk, bv,
        xb, mask_out, wqkvT, woT, w1T, w2T, bqkv, QSC);

    k_gemm_lds<2, false><<<dim3(12, 64), 256, 0, stream>>>(
        xb, wqkvT, bqkv, Qb, Kbuf, Vt, NROWS, 1536, 512);

    k_attn<<<dim3(16, 16, 4), 512, 0, stream>>>(
        Qb, Kbuf, Vt, tokens, atb, AVb, lpart);
    k_comb<<<2048, 256, 0, stream>>>(atb, AVb, lpart);

    k_gemm_lds<0, false><<<dim3(4, 64), 256, 0, stream>>>(
        atb, woT, bo, AVb, nullptr, nullptr, NROWS, 512, 512);

    // LN1: h = LN(av + x) -> bf16
    k_ln<true, true, false><<<NROWS / 4, 256, 0, stream>>>(
        AVb, xb, ln1_g, ln1_b, nullptr, hb);

    k_gemm_lds<0, true><<<dim3(8, 64), 256, 0, stream>>>(
        hb, w1T, b1, ff1b, nullptr, nullptr, NROWS, 1024, 512);
    k_gemm_lds<0, false><<<dim3(4, 64), 256, 0, stream>>>(
        ff1b, w2T, b2, ff2b, nullptr, nullptr, NROWS, 512, 1024);

    // LN2: out = LN(ff + h) -> f32 to d_out
    k_ln<true, true, true><<<NROWS / 4, 256, 0, stream>>>(
        ff2b, hb, ln2_g, ln2_b, out_f, nullptr);
}